// Round 1
// baseline (2639.802 us; speedup 1.0000x reference)
//
#include <hip/hip_runtime.h>

#define SEQ 4096
#define BATCH 512
#define INP 8
#define HID 30

__device__ __forceinline__ float sigmoid_f(float v) {
    return __builtin_amdgcn_rcpf(1.0f + __expf(-v));
}

// One wave (64 lanes) per batch chain.
// lane = j      (j<30): gate rows i_j (A) and g_j (B)
// lane = 32+j   (j<30): gate rows f_j (A) and o_j (B)
// lanes 30,31,62,63: clamped duplicates of j=29 (never stored)
__global__ __launch_bounds__(64) void lstm_chain_kernel(
    const float* __restrict__ x,     // [SEQ,BATCH,INP]
    const float* __restrict__ W_ih,  // [4H, INP]
    const float* __restrict__ W_hh,  // [4H, HID]
    const float* __restrict__ b_ih,  // [4H]
    const float* __restrict__ b_hh,  // [4H]
    const float* __restrict__ W_lin, // [1, HID]
    const float* __restrict__ b_lin, // [1]
    float* __restrict__ out)         // [SEQ,BATCH,1]
{
    const int lane = threadIdx.x;
    const int b    = blockIdx.x;
    const int j    = lane & 31;
    const int half = lane >> 5;
    const int jc   = j < HID ? j : HID - 1;
    const int ra   = half * HID + jc;            // i (half0) / f (half1)
    const int rb   = 2 * HID + half * HID + jc;  // g (half0) / o (half1)

    // ---- per-lane constant weights (registers) ----
    float wih_a[INP], wih_b[INP];
#pragma unroll
    for (int i = 0; i < INP; ++i) {
        wih_a[i] = W_ih[ra * INP + i];
        wih_b[i] = W_ih[rb * INP + i];
    }
    float whh_a[HID], whh_b[HID];
#pragma unroll
    for (int k = 0; k < HID; ++k) {
        whh_a[k] = W_hh[ra * HID + k];
        whh_b[k] = W_hh[rb * HID + k];
    }
    const float bias_a = b_ih[ra] + b_hh[ra];
    const float bias_b = b_ih[rb] + b_hh[rb];
    const float wlin   = (j < HID) ? W_lin[j] : 0.0f;
    const float blin   = b_lin[0];

    // gate-B activation: half0 -> tanh(x) = fma(rcp(1+e^{2x}), -2, 1)
    //                    half1 -> sigmoid(x) = rcp(1+e^{-x})
    const float mB   = half ? -1.0f : 2.0f;
    const float sclB = half ?  1.0f : -2.0f;
    const float addB = half ?  0.0f : 1.0f;

    __shared__ __align__(16) float s_h[32];
    if (lane < 32) s_h[lane] = 0.0f;
    asm volatile("s_waitcnt lgkmcnt(0)" ::: "memory");
    const float4* s_h4 = reinterpret_cast<const float4*>(s_h);

    float hrf[32];
#pragma unroll
    for (int q = 0; q < 32; ++q) hrf[q] = 0.0f;
    float c = 0.0f;

    // ---- x prefetch, distance 2 (static register rotation via unroll-2) ----
    const float4* xp0 = (const float4*)(x + ((size_t)0 * BATCH + b) * INP);
    float4 xA0 = xp0[0], xB0 = xp0[1];
    const float4* xp1 = (const float4*)(x + ((size_t)1 * BATCH + b) * INP);
    float4 xA1 = xp1[0], xB1 = xp1[1];

#define STEP(T, XA, XB) do {                                                  \
    float aa0 = bias_a, ab0 = bias_b;                                         \
    aa0 = fmaf((XA).x, wih_a[0], aa0);  ab0 = fmaf((XA).x, wih_b[0], ab0);    \
    aa0 = fmaf((XA).y, wih_a[1], aa0);  ab0 = fmaf((XA).y, wih_b[1], ab0);    \
    aa0 = fmaf((XA).z, wih_a[2], aa0);  ab0 = fmaf((XA).z, wih_b[2], ab0);    \
    aa0 = fmaf((XA).w, wih_a[3], aa0);  ab0 = fmaf((XA).w, wih_b[3], ab0);    \
    float aa1 = 0.0f, ab1 = 0.0f;                                             \
    aa1 = fmaf((XB).x, wih_a[4], aa1);  ab1 = fmaf((XB).x, wih_b[4], ab1);    \
    aa1 = fmaf((XB).y, wih_a[5], aa1);  ab1 = fmaf((XB).y, wih_b[5], ab1);    \
    aa1 = fmaf((XB).z, wih_a[6], aa1);  ab1 = fmaf((XB).z, wih_b[6], ab1);    \
    aa1 = fmaf((XB).w, wih_a[7], aa1);  ab1 = fmaf((XB).w, wih_b[7], ab1);    \
    _Pragma("unroll")                                                         \
    for (int k = 0; k < HID; k += 2) {                                        \
        aa0 = fmaf(hrf[k],   whh_a[k],   aa0);                                \
        ab0 = fmaf(hrf[k],   whh_b[k],   ab0);                                \
        aa1 = fmaf(hrf[k+1], whh_a[k+1], aa1);                                \
        ab1 = fmaf(hrf[k+1], whh_b[k+1], ab1);                                \
    }                                                                         \
    float ga = aa0 + aa1, gb = ab0 + ab1;                                     \
    float Av = sigmoid_f(ga);                                                 \
    float sB = __builtin_amdgcn_rcpf(1.0f + __expf(mB * gb));                 \
    float Bv = fmaf(sB, sclB, addB);                                          \
    float Ax = __shfl_xor(Av, 32, 64);                                        \
    float Bx = __shfl_xor(Bv, 32, 64);                                        \
    float ii = half ? Ax : Av;                                                \
    float gg = half ? Bx : Bv;                                                \
    float ff = half ? Av : Ax;                                                \
    float oo = half ? Bv : Bx;                                                \
    c = fmaf(ff, c, ii * gg);                                                 \
    float sc = __builtin_amdgcn_rcpf(1.0f + __expf(2.0f * c));                \
    float th = fmaf(sc, -2.0f, 1.0f);                                         \
    float h  = oo * th;                                                       \
    if (lane < HID) s_h[lane] = h;                                            \
    asm volatile("s_waitcnt lgkmcnt(0)" ::: "memory");                        \
    _Pragma("unroll")                                                         \
    for (int q = 0; q < 8; ++q) {                                             \
        float4 v = s_h4[q];                                                   \
        hrf[4*q+0] = v.x; hrf[4*q+1] = v.y;                                   \
        hrf[4*q+2] = v.z; hrf[4*q+3] = v.w;                                   \
    }                                                                         \
    float p = h * wlin;                                                       \
    p += __shfl_xor(p, 16, 64);                                               \
    p += __shfl_xor(p,  8, 64);                                               \
    p += __shfl_xor(p,  4, 64);                                               \
    p += __shfl_xor(p,  2, 64);                                               \
    p += __shfl_xor(p,  1, 64);                                               \
    if (lane == 0) out[(size_t)(T) * BATCH + b] = p + blin;                   \
} while (0)

    for (int t = 0; t < SEQ; t += 2) {
        STEP(t, xA0, xB0);
        {
            int tl = (t + 2 < SEQ) ? t + 2 : SEQ - 1;
            const float4* xp = (const float4*)(x + ((size_t)tl * BATCH + b) * INP);
            xA0 = xp[0]; xB0 = xp[1];
        }
        STEP(t + 1, xA1, xB1);
        {
            int tl = (t + 3 < SEQ) ? t + 3 : SEQ - 1;
            const float4* xp = (const float4*)(x + ((size_t)tl * BATCH + b) * INP);
            xA1 = xp[0]; xB1 = xp[1];
        }
    }
#undef STEP
}

extern "C" void kernel_launch(void* const* d_in, const int* in_sizes, int n_in,
                              void* d_out, int out_size, void* d_ws, size_t ws_size,
                              hipStream_t stream) {
    const float* x     = (const float*)d_in[0];
    const float* W_ih  = (const float*)d_in[1];
    const float* W_hh  = (const float*)d_in[2];
    const float* b_ih  = (const float*)d_in[3];
    const float* b_hh  = (const float*)d_in[4];
    const float* W_lin = (const float*)d_in[5];
    const float* b_lin = (const float*)d_in[6];
    float* out = (float*)d_out;

    lstm_chain_kernel<<<dim3(BATCH), dim3(64), 0, stream>>>(
        x, W_ih, W_hh, b_ih, b_hh, W_lin, b_lin, out);
}

// Round 2
// 2134.991 us; speedup vs baseline: 1.2364x; 1.2364x over previous
//
#include <hip/hip_runtime.h>

#define SEQ 4096
#define BATCH 512
#define INP 8
#define HID 30

typedef unsigned uint2v __attribute__((ext_vector_type(2)));

__device__ __forceinline__ float sigmoid_f(float v) {
    return __builtin_amdgcn_rcpf(1.0f + __expf(-v));
}

// v_permlane32_swap with vdst = vsrc = v:
//   returns {lo_rep = [v_lo | v_lo], hi_rep = [v_hi | v_hi]}
__device__ __forceinline__ void rep_halves(float v, float& lo_rep, float& hi_rep) {
#if __has_builtin(__builtin_amdgcn_permlane32_swap)
    uint2v r = __builtin_amdgcn_permlane32_swap(
        __float_as_uint(v), __float_as_uint(v), false, false);
    lo_rep = __uint_as_float(r.x);
    hi_rep = __uint_as_float(r.y);
#else
    float other = __shfl_xor(v, 32, 64);
    bool hi = (threadIdx.x & 32) != 0;
    lo_rep = hi ? other : v;
    hi_rep = hi ? v : other;
#endif
}

// One wave (64 lanes) per batch chain. No LDS, no spills.
// lane = j      (j<30): gate rows i_j (A) and g_j (B)
// lane = 32+j   (j<30): gate rows f_j (A) and o_j (B)
// h state lives in 30 SGPRs (v_readlane broadcast); gate FMAs are
// v_fma_f32 vdst, sgpr, vgpr, vacc (one SGPR source — legal).
__global__ __launch_bounds__(64, 1) void lstm_chain_kernel(
    const float* __restrict__ x,     // [SEQ,BATCH,INP]
    const float* __restrict__ W_ih,  // [4H, INP]
    const float* __restrict__ W_hh,  // [4H, HID]
    const float* __restrict__ b_ih,  // [4H]
    const float* __restrict__ b_hh,  // [4H]
    const float* __restrict__ W_lin, // [1, HID]
    const float* __restrict__ b_lin, // [1]
    float* __restrict__ out)         // [SEQ,BATCH,1]
{
    const int lane = threadIdx.x;
    const int b    = blockIdx.x;
    const int j    = lane & 31;
    const int half = lane >> 5;
    const int jc   = j < HID ? j : HID - 1;
    const int ra   = half * HID + jc;            // i (half0) / f (half1)
    const int rb   = 2 * HID + half * HID + jc;  // g (half0) / o (half1)

    // ---- per-lane constant weights (VGPRs) ----
    float wih_a[INP], wih_b[INP];
#pragma unroll
    for (int i = 0; i < INP; ++i) {
        wih_a[i] = W_ih[ra * INP + i];
        wih_b[i] = W_ih[rb * INP + i];
    }
    float whh_a[HID], whh_b[HID];
#pragma unroll
    for (int k = 0; k < HID; ++k) {
        whh_a[k] = W_hh[ra * HID + k];
        whh_b[k] = W_hh[rb * HID + k];
    }
    const float bias_a = b_ih[ra] + b_hh[ra];
    const float bias_b = b_ih[rb] + b_hh[rb];
    const float blin   = b_lin[0];

    // W_lin is wave-uniform; pin it into VGPRs so the projection FMA is
    // (SGPR h) x (VGPR w) — never two SGPR sources.
    float wlin_r[HID];
#pragma unroll
    for (int k = 0; k < HID; ++k) {
        float w = W_lin[k];
        asm volatile("" : "+v"(w));
        wlin_r[k] = w;
    }

    // gate-B activation: half0 -> tanh(x) = fma(rcp(1+e^{2x}), -2, 1)
    //                    half1 -> sigmoid(x) = rcp(1+e^{-x})
    const float mB   = half ? -1.0f : 2.0f;
    const float sclB = half ?  1.0f : -2.0f;
    const float addB = half ?  0.0f : 1.0f;

    // h state broadcast to all lanes, kept in SGPRs via readlane
    float hs[HID];
#pragma unroll
    for (int k = 0; k < HID; ++k) hs[k] = 0.0f;
    float c = 0.0f;

    // ---- x prefetch, distance 2 (static register rotation via unroll-2) ----
    const float4* xp0 = (const float4*)(x + ((size_t)0 * BATCH + b) * INP);
    float4 xA0 = xp0[0], xB0 = xp0[1];
    const float4* xp1 = (const float4*)(x + ((size_t)1 * BATCH + b) * INP);
    float4 xA1 = xp1[0], xB1 = xp1[1];

#define STEP(T, XA, XB) do {                                                  \
    float aa0 = bias_a, ab0 = bias_b;                                         \
    aa0 = fmaf((XA).x, wih_a[0], aa0);  ab0 = fmaf((XA).x, wih_b[0], ab0);    \
    aa0 = fmaf((XA).y, wih_a[1], aa0);  ab0 = fmaf((XA).y, wih_b[1], ab0);    \
    aa0 = fmaf((XA).z, wih_a[2], aa0);  ab0 = fmaf((XA).z, wih_b[2], ab0);    \
    aa0 = fmaf((XA).w, wih_a[3], aa0);  ab0 = fmaf((XA).w, wih_b[3], ab0);    \
    float aa1 = 0.0f, ab1 = 0.0f;                                             \
    aa1 = fmaf((XB).x, wih_a[4], aa1);  ab1 = fmaf((XB).x, wih_b[4], ab1);    \
    aa1 = fmaf((XB).y, wih_a[5], aa1);  ab1 = fmaf((XB).y, wih_b[5], ab1);    \
    aa1 = fmaf((XB).z, wih_a[6], aa1);  ab1 = fmaf((XB).z, wih_b[6], ab1);    \
    aa1 = fmaf((XB).w, wih_a[7], aa1);  ab1 = fmaf((XB).w, wih_b[7], ab1);    \
    _Pragma("unroll")                                                         \
    for (int k = 0; k < HID; k += 2) {                                        \
        aa0 = fmaf(hs[k],   whh_a[k],   aa0);                                 \
        ab0 = fmaf(hs[k],   whh_b[k],   ab0);                                 \
        aa1 = fmaf(hs[k+1], whh_a[k+1], aa1);                                 \
        ab1 = fmaf(hs[k+1], whh_b[k+1], ab1);                                 \
    }                                                                         \
    float ga = aa0 + aa1, gb = ab0 + ab1;                                     \
    float Av = sigmoid_f(ga);                                                 \
    float sB = __builtin_amdgcn_rcpf(1.0f + __expf(mB * gb));                 \
    float Bv = fmaf(sB, sclB, addB);                                          \
    float ii, ff, gg, oo;                                                     \
    rep_halves(Av, ii, ff);                                                   \
    rep_halves(Bv, gg, oo);                                                   \
    c = fmaf(ff, c, ii * gg);                                                 \
    float sc = __builtin_amdgcn_rcpf(1.0f + __expf(2.0f * c));                \
    float h  = oo * fmaf(sc, -2.0f, 1.0f);                                    \
    _Pragma("unroll")                                                         \
    for (int k = 0; k < HID; ++k)                                             \
        hs[k] = __uint_as_float((unsigned)__builtin_amdgcn_readlane(          \
                    (int)__float_as_uint(h), k));                             \
    float p0 = 0.0f, p1 = 0.0f;                                               \
    _Pragma("unroll")                                                         \
    for (int k = 0; k < HID; k += 2) {                                        \
        p0 = fmaf(hs[k],   wlin_r[k],   p0);                                  \
        p1 = fmaf(hs[k+1], wlin_r[k+1], p1);                                  \
    }                                                                         \
    if (lane == 0) out[(size_t)(T) * BATCH + b] = p0 + p1 + blin;             \
} while (0)

    for (int t = 0; t < SEQ; t += 2) {
        STEP(t, xA0, xB0);
        {
            int tl = (t + 2 < SEQ) ? t + 2 : SEQ - 1;
            const float4* xp = (const float4*)(x + ((size_t)tl * BATCH + b) * INP);
            xA0 = xp[0]; xB0 = xp[1];
        }
        STEP(t + 1, xA1, xB1);
        {
            int tl = (t + 3 < SEQ) ? t + 3 : SEQ - 1;
            const float4* xp = (const float4*)(x + ((size_t)tl * BATCH + b) * INP);
            xA1 = xp[0]; xB1 = xp[1];
        }
    }
#undef STEP
}

extern "C" void kernel_launch(void* const* d_in, const int* in_sizes, int n_in,
                              void* d_out, int out_size, void* d_ws, size_t ws_size,
                              hipStream_t stream) {
    const float* x     = (const float*)d_in[0];
    const float* W_ih  = (const float*)d_in[1];
    const float* W_hh  = (const float*)d_in[2];
    const float* b_ih  = (const float*)d_in[3];
    const float* b_hh  = (const float*)d_in[4];
    const float* W_lin = (const float*)d_in[5];
    const float* b_lin = (const float*)d_in[6];
    float* out = (float*)d_out;

    lstm_chain_kernel<<<dim3(BATCH), dim3(64), 0, stream>>>(
        x, W_ih, W_hh, b_ih, b_hh, W_lin, b_lin, out);
}